// Round 6
// baseline (64.549 us; speedup 1.0000x reference)
//
#include <hip/hip_runtime.h>
#include <hip/hip_bf16.h>

#define NEG 0.2f
#define LOG2E 1.4426950408889634f

typedef __attribute__((ext_vector_type(8))) short bf16x8;
typedef __attribute__((ext_vector_type(4))) float f32x4;
typedef __attribute__((ext_vector_type(16))) float f32x16;
typedef __attribute__((ext_vector_type(4))) int int4v;

__device__ __forceinline__ float lrelu(float t){ return fmaxf(t, NEG * t); }
__device__ __forceinline__ float fast_exp2(float x){
  float r; asm("v_exp_f32 %0, %1" : "=v"(r) : "v"(x)); return r;
}
__device__ __forceinline__ unsigned short f2bf(float f){   // RNE
  union { float f; unsigned int u; } v; v.f = f;
  unsigned int r = v.u + 0x7FFFu + ((v.u >> 16) & 1u);
  return (unsigned short)(r >> 16);
}

// ---------------- K0: Wt[o][k] = bf16(W[k][o]), once ----------------
__global__ __launch_bounds__(256) void k0_wt(const float* __restrict__ W,
                                             unsigned short* __restrict__ Wt){
  __shared__ __align__(16) unsigned short wl[128*136];
  const int t = threadIdx.x;
  {
    const int k = t >> 1, oh = (t & 1) * 64;
#pragma unroll 8
    for (int e = 0; e < 64; ++e)
      wl[(oh + e)*136 + k] = f2bf(W[k*128 + oh + e]);
  }
  __syncthreads();
  {
    const int o = t >> 1, ks = (t & 1) * 64;
#pragma unroll
    for (int g = 0; g < 8; ++g){
      int4v v = *(const int4v*)(wl + o*136 + ks + g*8);
      *(int4v*)(Wt + o*128 + ks + g*8) = v;
    }
  }
}

// ---------------- K1: h^T via MFMA + scaled s_src/s_dst + ht store ----------------
__global__ __launch_bounds__(256) void k1_fused(const float* __restrict__ x,
                                                const unsigned short* __restrict__ Wt,
                                                const float* __restrict__ a,
                                                unsigned short* __restrict__ ht,
                                                float* __restrict__ ssrcL,
                                                float* __restrict__ sdstL){
  __shared__ __align__(16) unsigned short wtl[128*136];
  __shared__ __align__(16) unsigned short xl[32*136];
  __shared__ __align__(16) unsigned short tlw[128*34];
  __shared__ float sred[2][4][2][16];
  const int t = threadIdx.x;
  const int bx = blockIdx.x;                 // b*64 + jt
  const int b  = bx >> 6;
  const int jt = bx & 63;
  const long rowbase = (long)bx * 32;
  {
    const int o = t >> 1, seg = (t & 1) * 64;
    const int4v* src = (const int4v*)(Wt + o*128 + seg);
    int4v* dst = (int4v*)(wtl + o*136 + seg);
#pragma unroll
    for (int g = 0; g < 8; ++g) dst[g] = src[g];
  }
  {
    const int i = t >> 3, ks = (t & 7) * 16;
    const f32x4* src = (const f32x4*)(x + (rowbase + i)*128 + ks);
    unsigned int q[8];
#pragma unroll
    for (int g = 0; g < 4; ++g){
      f32x4 v = src[g];
      q[g*2]   = (unsigned)f2bf(v[0]) | ((unsigned)f2bf(v[1]) << 16);
      q[g*2+1] = (unsigned)f2bf(v[2]) | ((unsigned)f2bf(v[3]) << 16);
    }
    int4v* dst = (int4v*)(xl + i*136 + ks);
    dst[0] = *(int4v*)&q[0];
    dst[1] = *(int4v*)&q[4];
  }
  __syncthreads();
  const int w = t >> 6, lane = t & 63, lr = lane & 15, hi = lane >> 4;
  f32x4 zro = {0.f, 0.f, 0.f, 0.f};
  f32x4 acc00 = zro, acc01 = zro, acc10 = zro, acc11 = zro;
#pragma unroll
  for (int ks = 0; ks < 4; ++ks){
    const bf16x8 a0 = *(const bf16x8*)(wtl + (w*32      + lr)*136 + ks*32 + hi*8);
    const bf16x8 a1 = *(const bf16x8*)(wtl + (w*32 + 16 + lr)*136 + ks*32 + hi*8);
    const bf16x8 b0 = *(const bf16x8*)(xl + (     lr)*136 + ks*32 + hi*8);
    const bf16x8 b1 = *(const bf16x8*)(xl + (16 + lr)*136 + ks*32 + hi*8);
    acc00 = __builtin_amdgcn_mfma_f32_16x16x32_bf16(a0, b0, acc00, 0, 0, 0);
    acc01 = __builtin_amdgcn_mfma_f32_16x16x32_bf16(a0, b1, acc01, 0, 0, 0);
    acc10 = __builtin_amdgcn_mfma_f32_16x16x32_bf16(a1, b0, acc10, 0, 0, 0);
    acc11 = __builtin_amdgcn_mfma_f32_16x16x32_bf16(a1, b1, acc11, 0, 0, 0);
  }
  {
    const f32x4 as0 = *(const f32x4*)(a +       w*32      + hi*4);
    const f32x4 as1 = *(const f32x4*)(a +       w*32 + 16 + hi*4);
    const f32x4 ad0 = *(const f32x4*)(a + 128 + w*32      + hi*4);
    const f32x4 ad1 = *(const f32x4*)(a + 128 + w*32 + 16 + hi*4);
    float ps0, ps1, pd0, pd1;
    {
      f32x4 u = acc00*as0 + acc10*as1;  ps0 = u[0]+u[1]+u[2]+u[3];
      f32x4 v = acc01*as0 + acc11*as1;  ps1 = v[0]+v[1]+v[2]+v[3];
      f32x4 p = acc00*ad0 + acc10*ad1;  pd0 = p[0]+p[1]+p[2]+p[3];
      f32x4 r = acc01*ad0 + acc11*ad1;  pd1 = r[0]+r[1]+r[2]+r[3];
    }
#pragma unroll
    for (int off = 16; off <= 32; off <<= 1){
      ps0 += __shfl_xor(ps0, off); ps1 += __shfl_xor(ps1, off);
      pd0 += __shfl_xor(pd0, off); pd1 += __shfl_xor(pd1, off);
    }
    if (hi == 0){
      sred[0][w][0][lr] = ps0; sred[0][w][1][lr] = ps1;
      sred[1][w][0][lr] = pd0; sred[1][w][1][lr] = pd1;
    }
  }
#pragma unroll
  for (int q = 0; q < 4; ++q){
    tlw[(w*32      + hi*4 + q)*34      + lr] = f2bf(acc00[q]);
    tlw[(w*32      + hi*4 + q)*34 + 16 + lr] = f2bf(acc01[q]);
    tlw[(w*32 + 16 + hi*4 + q)*34      + lr] = f2bf(acc10[q]);
    tlw[(w*32 + 16 + hi*4 + q)*34 + 16 + lr] = f2bf(acc11[q]);
  }
  __syncthreads();
  {
    const int o = t >> 1, jseg = (t & 1) * 16;
    const unsigned int* src = (const unsigned int*)(tlw + o*34 + jseg);
    unsigned int p[8];
#pragma unroll
    for (int g = 0; g < 8; ++g) p[g] = src[g];
    unsigned short* dst = ht + (long)b*262144 + (long)o*2048 + jt*32 + jseg;
    ((int4v*)dst)[0] = *(int4v*)&p[0];
    ((int4v*)dst)[1] = *(int4v*)&p[4];
  }
  if (t < 64){
    const int sel = t >> 5, jl = t & 31;
    const int ig = jl >> 4, l2 = jl & 15;
    const float s = sred[sel][0][ig][l2] + sred[sel][1][ig][l2]
                  + sred[sel][2][ig][l2] + sred[sel][3][ig][l2];
    if (sel == 0) ssrcL[rowbase + jl] = s * LOG2E;
    else          sdstL[rowbase + jl] = s * LOG2E;
  }
}

// ---------------- K2: per-row C_i = m_L + log2(sum_j 2^(lrelu(siL+sjL)-m_L)) ----------------
__global__ __launch_bounds__(256) void k2_ml(const float* __restrict__ ssrcL,
                                             const float* __restrict__ sdstL,
                                             float* __restrict__ carr){
  const int lane = threadIdx.x & 63;
  const long row = (long)blockIdx.x * 4 + (threadIdx.x >> 6);
  const int b = (int)(row >> 11);
  const float siL = ssrcL[row];
  const float* sd = sdstL + (long)b*2048;
  float mx = -3.4e38f;
#pragma unroll
  for (int k = 0; k < 8; ++k){
    f32x4 v = *(const f32x4*)(sd + lane*4 + k*256);
    mx = fmaxf(mx, fmaxf(fmaxf(v[0], v[1]), fmaxf(v[2], v[3])));
  }
#pragma unroll
  for (int off = 1; off <= 32; off <<= 1) mx = fmaxf(mx, __shfl_xor(mx, off));
  const float mL = lrelu(siL + mx);
  float sum = 0.f;
#pragma unroll
  for (int k = 0; k < 8; ++k){
    f32x4 v = *(const f32x4*)(sd + lane*4 + k*256);
#pragma unroll
    for (int e = 0; e < 4; ++e) sum += fast_exp2(lrelu(siL + v[e]) - mL);
  }
#pragma unroll
  for (int off = 1; off <= 32; off <<= 1) sum += __shfl_xor(sum, off);
  if (lane == 0) carr[row] = mL + __log2f(sum);
}

// ---------------- K3: out = LR( (adj + alpha) @ h ), 32x32x16 MFMA ----------------
// grid 512 = 8b x 64 tiles (BM=32, XCD-swizzled); block 128 = 2 INDEPENDENT waves.
// Wave w owns K-half w (j in [w*1024, w*1024+1024)), all 32 rows x all 128 n.
// Per 64-j step: wave stages its [128 o][64 j] bf16 tile via global_load_lds
// (linear LDS dest; XOR-swizzle applied on the SOURCE address and on the read
// -- rule #21), double-buffered; adj/sd double-set register pipeline (lead 2);
// counted s_waitcnt vmcnt(16) per step (T4: stage loads drain, adj stays in flight).
// NO barriers in the main loop (waves fully independent); split-K reduce at end.
__global__ __launch_bounds__(128) void k3_main(const float* __restrict__ adj,
                                               const unsigned short* __restrict__ ht,
                                               const float* __restrict__ ssrcL,
                                               const float* __restrict__ sdstL,
                                               const float* __restrict__ carr,
                                               float* __restrict__ out){
  __shared__ __align__(16) char smem[65536];   // tl[2buf][2kh][128o][64j] bf16 = 64KB; red(16KB) aliased
  unsigned short (*tl)[2][128][64] = (unsigned short (*)[2][128][64])smem;
  float* red = (float*)smem;
  const int t   = threadIdx.x;
  const int bxr = blockIdx.x;
  const int bx  = ((bxr & 7) << 6) | (bxr >> 3);   // batch -> XCD
  const int b   = bx >> 6;
  const int i0  = (bx & 63) * 32;
  const int w   = t >> 6, lane = t & 63;
  const int r32 = lane & 31, ks = lane >> 5;
  const long rowg = (long)b*2048 + i0 + r32;
  const float siL = ssrcL[rowg];
  const float Ci  = carr[rowg];
  const float* adjrow = adj + rowg*2048 + w*1024;
  const float* sdb    = sdstL + (long)b*2048 + w*1024;
  // staging source: lane l covers rows o = ii*8 + (l>>3), physical chunk l&7;
  // logical chunk = (l&7) ^ (o&7) = (l&7) ^ ((l>>3)&7)  (source pre-swizzle)
  const unsigned short* sgbase = ht + (long)b*262144 + w*1024
                               + ((lane & 7) ^ ((lane >> 3) & 7)) * 8
                               + (long)(lane >> 3) * 2048;

#define K3_STAGE(BB, JB) do{                                                     \
    _Pragma("unroll")                                                            \
    for (int ii = 0; ii < 16; ++ii){                                             \
      __builtin_amdgcn_global_load_lds(                                          \
        (const __attribute__((address_space(1))) void*)(sgbase + (JB) + ii*16384),\
        (__attribute__((address_space(3))) void*)&tl[BB][w][ii*8][0], 16, 0, 0); \
    }                                                                            \
    __builtin_amdgcn_sched_barrier(0);                                           \
  }while(0)

#define K3_LOADSET(SL, JB) do{                                                   \
    _Pragma("unroll")                                                            \
    for (int g = 0; g < 4; ++g){                                                 \
      av[SL][g*2]   = *(const f32x4*)(adjrow + (JB) + g*16 + ks*8);              \
      av[SL][g*2+1] = *(const f32x4*)(adjrow + (JB) + g*16 + ks*8 + 4);          \
      dv[SL][g*2]   = *(const f32x4*)(sdb    + (JB) + g*16 + ks*8);              \
      dv[SL][g*2+1] = *(const f32x4*)(sdb    + (JB) + g*16 + ks*8 + 4);          \
    }                                                                            \
  }while(0)

  f32x4 av[2][8], dv[2][8];
  f32x16 acc[4];
#pragma unroll
  for (int f = 0; f < 4; ++f)
#pragma unroll
    for (int e = 0; e < 16; ++e) acc[f][e] = 0.f;

  // ---- prologue ----
  K3_STAGE(0, 0);
  K3_LOADSET(0, 0);
  K3_LOADSET(1, 64);
  asm volatile("s_waitcnt vmcnt(32)" ::: "memory");   // stage(0) done; 32 adj/sd in flight
  __builtin_amdgcn_sched_barrier(0);

#pragma unroll
  for (int i = 0; i < 16; ++i){
    const int cur = i & 1;
    if (i < 15) K3_STAGE(cur ^ 1, (i + 1) * 64);      // next tile -> other buffer
    // weights for this step from register set [cur]
    bf16x8 af[4];
#pragma unroll
    for (int g = 0; g < 4; ++g){
      float wv[8];
#pragma unroll
      for (int e = 0; e < 4; ++e){
        wv[e]     = av[cur][g*2][e]   + fast_exp2(lrelu(siL + dv[cur][g*2][e])   - Ci);
        wv[4 + e] = av[cur][g*2+1][e] + fast_exp2(lrelu(siL + dv[cur][g*2+1][e]) - Ci);
      }
      const unsigned int p01 = __builtin_amdgcn_perm(__float_as_uint(wv[1]), __float_as_uint(wv[0]), 0x07060302u);
      const unsigned int p23 = __builtin_amdgcn_perm(__float_as_uint(wv[3]), __float_as_uint(wv[2]), 0x07060302u);
      const unsigned int p45 = __builtin_amdgcn_perm(__float_as_uint(wv[5]), __float_as_uint(wv[4]), 0x07060302u);
      const unsigned int p67 = __builtin_amdgcn_perm(__float_as_uint(wv[7]), __float_as_uint(wv[6]), 0x07060302u);
      int4v ai = {(int)p01, (int)p23, (int)p45, (int)p67};
      af[g] = *(bf16x8*)&ai;
    }
    if (i < 14) K3_LOADSET(cur, (i + 2) * 64);        // refill set for step i+2
    // MFMA: 4 k-subs x 4 n-frags on current buffer (swizzled read)
#pragma unroll
    for (int g = 0; g < 4; ++g){
      const int cph = ((g*2 + ks) ^ (lane & 7)) * 8;
#pragma unroll
      for (int f = 0; f < 4; ++f){
        const bf16x8 bf = *(const bf16x8*)&tl[cur][w][f*32 + r32][cph];
        acc[f] = __builtin_amdgcn_mfma_f32_32x32x16_bf16(af[g], bf, acc[f], 0, 0, 0);
      }
    }
    if (i < 14)      asm volatile("s_waitcnt vmcnt(16)" ::: "memory"); // stage done, adj in flight
    else if (i == 14) asm volatile("s_waitcnt vmcnt(0)"  ::: "memory"); // last stage must land
    __builtin_amdgcn_sched_barrier(0);
  }
#undef K3_STAGE
#undef K3_LOADSET

  // ---- epilogue: split-K reduce via LDS (aliases tl), then lrelu + store ----
  __syncthreads();
  if (w == 1){
#pragma unroll
    for (int f = 0; f < 4; ++f)
#pragma unroll
      for (int rg = 0; rg < 16; ++rg){
        const int rr = (rg & 3) + 8*(rg >> 2) + 4*ks;
        red[rr*128 + f*32 + r32] = acc[f][rg];
      }
  }
  __syncthreads();
  if (w == 0){
#pragma unroll
    for (int f = 0; f < 4; ++f)
#pragma unroll
      for (int rg = 0; rg < 16; ++rg){
        const int rr = (rg & 3) + 8*(rg >> 2) + 4*ks;
        const float v = acc[f][rg] + red[rr*128 + f*32 + r32];
        out[((long)b*2048 + i0 + rr)*128 + f*32 + r32] = lrelu(v);
      }
  }
}

extern "C" void kernel_launch(void* const* d_in, const int* in_sizes, int n_in,
                              void* d_out, int out_size, void* d_ws, size_t ws_size,
                              hipStream_t stream){
  const float* x   = (const float*)d_in[0];
  const float* adj = (const float*)d_in[1];
  const float* W   = (const float*)d_in[2];
  const float* a   = (const float*)d_in[3];
  float* out = (float*)d_out;
  char* ws = (char*)d_ws;

  unsigned short* ht    = (unsigned short*)(ws);              // 4 MB
  float*          ssrcL = (float*)(ws + 4194304);             // 64 KB
  float*          sdstL = (float*)(ws + 4259840);             // 64 KB
  float*          carr  = (float*)(ws + 4325376);             // 64 KB
  unsigned short* Wt    = (unsigned short*)(ws + 4390912);    // 32 KB

  k0_wt   <<<1,    256, 0, stream>>>(W, Wt);
  k1_fused<<<512,  256, 0, stream>>>(x, Wt, a, ht, ssrcL, sdstL);
  k2_ml   <<<4096, 256, 0, stream>>>(ssrcL, sdstL, carr);
  k3_main <<<512,  128, 0, stream>>>(adj, ht, ssrcL, sdstL, carr, out);
}

// Round 7
// 52.656 us; speedup vs baseline: 1.2259x; 1.2259x over previous
//
#include <hip/hip_runtime.h>
#include <hip/hip_bf16.h>

#define NEG 0.2f
#define LOG2E 1.4426950408889634f

typedef __attribute__((ext_vector_type(8))) short bf16x8;
typedef __attribute__((ext_vector_type(4))) float f32x4;
typedef __attribute__((ext_vector_type(16))) float f32x16;
typedef __attribute__((ext_vector_type(4))) int int4v;

__device__ __forceinline__ float lrelu(float t){ return fmaxf(t, NEG * t); }
__device__ __forceinline__ float fast_exp2(float x){
  float r; asm("v_exp_f32 %0, %1" : "=v"(r) : "v"(x)); return r;
}
__device__ __forceinline__ unsigned short f2bf(float f){   // RNE
  union { float f; unsigned int u; } v; v.f = f;
  unsigned int r = v.u + 0x7FFFu + ((v.u >> 16) & 1u);
  return (unsigned short)(r >> 16);
}

// ---------------- K0: Wt[o][k] = bf16(W[k][o]), once ----------------
__global__ __launch_bounds__(256) void k0_wt(const float* __restrict__ W,
                                             unsigned short* __restrict__ Wt){
  __shared__ __align__(16) unsigned short wl[128*136];
  const int t = threadIdx.x;
  {
    const int k = t >> 1, oh = (t & 1) * 64;
#pragma unroll 8
    for (int e = 0; e < 64; ++e)
      wl[(oh + e)*136 + k] = f2bf(W[k*128 + oh + e]);
  }
  __syncthreads();
  {
    const int o = t >> 1, ks = (t & 1) * 64;
#pragma unroll
    for (int g = 0; g < 8; ++g){
      int4v v = *(const int4v*)(wl + o*136 + ks + g*8);
      *(int4v*)(Wt + o*128 + ks + g*8) = v;
    }
  }
}

// ---------------- K1: h^T via MFMA + scaled s_src/s_dst + ht store ----------------
__global__ __launch_bounds__(256) void k1_fused(const float* __restrict__ x,
                                                const unsigned short* __restrict__ Wt,
                                                const float* __restrict__ a,
                                                unsigned short* __restrict__ ht,
                                                float* __restrict__ ssrcL,
                                                float* __restrict__ sdstL){
  __shared__ __align__(16) unsigned short wtl[128*136];
  __shared__ __align__(16) unsigned short xl[32*136];
  __shared__ __align__(16) unsigned short tlw[128*34];
  __shared__ float sred[2][4][2][16];
  const int t = threadIdx.x;
  const int bx = blockIdx.x;                 // b*64 + jt
  const int b  = bx >> 6;
  const int jt = bx & 63;
  const long rowbase = (long)bx * 32;
  {
    const int o = t >> 1, seg = (t & 1) * 64;
    const int4v* src = (const int4v*)(Wt + o*128 + seg);
    int4v* dst = (int4v*)(wtl + o*136 + seg);
#pragma unroll
    for (int g = 0; g < 8; ++g) dst[g] = src[g];
  }
  {
    const int i = t >> 3, ks = (t & 7) * 16;
    const f32x4* src = (const f32x4*)(x + (rowbase + i)*128 + ks);
    unsigned int q[8];
#pragma unroll
    for (int g = 0; g < 4; ++g){
      f32x4 v = src[g];
      q[g*2]   = (unsigned)f2bf(v[0]) | ((unsigned)f2bf(v[1]) << 16);
      q[g*2+1] = (unsigned)f2bf(v[2]) | ((unsigned)f2bf(v[3]) << 16);
    }
    int4v* dst = (int4v*)(xl + i*136 + ks);
    dst[0] = *(int4v*)&q[0];
    dst[1] = *(int4v*)&q[4];
  }
  __syncthreads();
  const int w = t >> 6, lane = t & 63, lr = lane & 15, hi = lane >> 4;
  f32x4 zro = {0.f, 0.f, 0.f, 0.f};
  f32x4 acc00 = zro, acc01 = zro, acc10 = zro, acc11 = zro;
#pragma unroll
  for (int ks = 0; ks < 4; ++ks){
    const bf16x8 a0 = *(const bf16x8*)(wtl + (w*32      + lr)*136 + ks*32 + hi*8);
    const bf16x8 a1 = *(const bf16x8*)(wtl + (w*32 + 16 + lr)*136 + ks*32 + hi*8);
    const bf16x8 b0 = *(const bf16x8*)(xl + (     lr)*136 + ks*32 + hi*8);
    const bf16x8 b1 = *(const bf16x8*)(xl + (16 + lr)*136 + ks*32 + hi*8);
    acc00 = __builtin_amdgcn_mfma_f32_16x16x32_bf16(a0, b0, acc00, 0, 0, 0);
    acc01 = __builtin_amdgcn_mfma_f32_16x16x32_bf16(a0, b1, acc01, 0, 0, 0);
    acc10 = __builtin_amdgcn_mfma_f32_16x16x32_bf16(a1, b0, acc10, 0, 0, 0);
    acc11 = __builtin_amdgcn_mfma_f32_16x16x32_bf16(a1, b1, acc11, 0, 0, 0);
  }
  {
    const f32x4 as0 = *(const f32x4*)(a +       w*32      + hi*4);
    const f32x4 as1 = *(const f32x4*)(a +       w*32 + 16 + hi*4);
    const f32x4 ad0 = *(const f32x4*)(a + 128 + w*32      + hi*4);
    const f32x4 ad1 = *(const f32x4*)(a + 128 + w*32 + 16 + hi*4);
    float ps0, ps1, pd0, pd1;
    {
      f32x4 u = acc00*as0 + acc10*as1;  ps0 = u[0]+u[1]+u[2]+u[3];
      f32x4 v = acc01*as0 + acc11*as1;  ps1 = v[0]+v[1]+v[2]+v[3];
      f32x4 p = acc00*ad0 + acc10*ad1;  pd0 = p[0]+p[1]+p[2]+p[3];
      f32x4 r = acc01*ad0 + acc11*ad1;  pd1 = r[0]+r[1]+r[2]+r[3];
    }
#pragma unroll
    for (int off = 16; off <= 32; off <<= 1){
      ps0 += __shfl_xor(ps0, off); ps1 += __shfl_xor(ps1, off);
      pd0 += __shfl_xor(pd0, off); pd1 += __shfl_xor(pd1, off);
    }
    if (hi == 0){
      sred[0][w][0][lr] = ps0; sred[0][w][1][lr] = ps1;
      sred[1][w][0][lr] = pd0; sred[1][w][1][lr] = pd1;
    }
  }
#pragma unroll
  for (int q = 0; q < 4; ++q){
    tlw[(w*32      + hi*4 + q)*34      + lr] = f2bf(acc00[q]);
    tlw[(w*32      + hi*4 + q)*34 + 16 + lr] = f2bf(acc01[q]);
    tlw[(w*32 + 16 + hi*4 + q)*34      + lr] = f2bf(acc10[q]);
    tlw[(w*32 + 16 + hi*4 + q)*34 + 16 + lr] = f2bf(acc11[q]);
  }
  __syncthreads();
  {
    const int o = t >> 1, jseg = (t & 1) * 16;
    const unsigned int* src = (const unsigned int*)(tlw + o*34 + jseg);
    unsigned int p[8];
#pragma unroll
    for (int g = 0; g < 8; ++g) p[g] = src[g];
    unsigned short* dst = ht + (long)b*262144 + (long)o*2048 + jt*32 + jseg;
    ((int4v*)dst)[0] = *(int4v*)&p[0];
    ((int4v*)dst)[1] = *(int4v*)&p[4];
  }
  if (t < 64){
    const int sel = t >> 5, jl = t & 31;
    const int ig = jl >> 4, l2 = jl & 15;
    const float s = sred[sel][0][ig][l2] + sred[sel][1][ig][l2]
                  + sred[sel][2][ig][l2] + sred[sel][3][ig][l2];
    if (sel == 0) ssrcL[rowbase + jl] = s * LOG2E;
    else          sdstL[rowbase + jl] = s * LOG2E;
  }
}

// ---------------- K2: per-row C_i = m_L + log2(sum_j 2^(lrelu(siL+sjL)-m_L)) ----------------
__global__ __launch_bounds__(256) void k2_ml(const float* __restrict__ ssrcL,
                                             const float* __restrict__ sdstL,
                                             float* __restrict__ carr){
  const int lane = threadIdx.x & 63;
  const long row = (long)blockIdx.x * 4 + (threadIdx.x >> 6);
  const int b = (int)(row >> 11);
  const float siL = ssrcL[row];
  const float* sd = sdstL + (long)b*2048;
  float mx = -3.4e38f;
#pragma unroll
  for (int k = 0; k < 8; ++k){
    f32x4 v = *(const f32x4*)(sd + lane*4 + k*256);
    mx = fmaxf(mx, fmaxf(fmaxf(v[0], v[1]), fmaxf(v[2], v[3])));
  }
#pragma unroll
  for (int off = 1; off <= 32; off <<= 1) mx = fmaxf(mx, __shfl_xor(mx, off));
  const float mL = lrelu(siL + mx);
  float sum = 0.f;
#pragma unroll
  for (int k = 0; k < 8; ++k){
    f32x4 v = *(const f32x4*)(sd + lane*4 + k*256);
#pragma unroll
    for (int e = 0; e < 4; ++e) sum += fast_exp2(lrelu(siL + v[e]) - mL);
  }
#pragma unroll
  for (int off = 1; off <= 32; off <<= 1) sum += __shfl_xor(sum, off);
  if (lane == 0) carr[row] = mL + __log2f(sum);
}

// ---------------- K3: out = LR( (adj + alpha) @ h ), cooperative-weight MFMA ----------------
// grid 512 = 8b x 64 tiles (BM=32, XCD-swizzled); block 256 = 4 waves.
// Wave w owns output cols [w*32, w*32+32), FULL K (no split-K): acc = 1x f32x16.
// Per BK=64 step: each wave computes weights for its 16-j slice (8 els/lane),
// shares via chunk-XOR-swizzled wtile; stages its OWN 32 ht-rows via
// global_load_lds (pre-swizzled source, rule #21). One barrier/step with
// counted vmcnt(8) -> next-tile stage + adj set stay in flight (T3/T4).
__global__ __launch_bounds__(256, 2) void k3_main(const float* __restrict__ adj,
                                                  const unsigned short* __restrict__ ht,
                                                  const float* __restrict__ ssrcL,
                                                  const float* __restrict__ sdstL,
                                                  const float* __restrict__ carr,
                                                  float* __restrict__ out){
  __shared__ __align__(16) unsigned short httile[2][128][64];  // 32 KB (o-rows x j)
  __shared__ __align__(16) unsigned short wtile[2][32][64];    // 8 KB  (i-rows x j)
  const int t    = threadIdx.x;
  const int bxr  = blockIdx.x;
  const int bx   = ((bxr & 7) << 6) | (bxr >> 3);   // batch -> one XCD
  const int b    = bx >> 6;
  const int i0   = (bx & 63) * 32;
  const int w    = t >> 6, lane = t & 63;
  const int r32  = lane & 31, hl = lane >> 5;
  const int r7   = r32 & 7;
  const int wchunk = (w*2 + hl) ^ r7;               // wtile write position
  const long rowg = (long)b*2048 + i0 + r32;
  const float siL = ssrcL[rowg];
  const float Ci  = carr[rowg];
  const float* adjL = adj + rowg*2048 + w*16 + hl*8;      // this lane's weight slice
  const float* sdbL = sdstL + (long)b*2048 + w*16 + hl*8;
  // staging source (this wave's 32 o-rows, source pre-swizzled by j-chunk):
  const unsigned short* sgbase = ht + (long)b*262144
                               + (long)(w*32 + (lane >> 3))*2048
                               + ((lane & 7) ^ (lane >> 3)) * 8;

  f32x16 acc;
#pragma unroll
  for (int e = 0; e < 16; ++e) acc[e] = 0.f;
  f32x4 aA0, aA1, dA0, dA1, aB0, aB1, dB0, dB1;

  // ---- prologue: stage tile0 -> buf0; adj/sd sets for steps 0,1 ----
#pragma unroll
  for (int it = 0; it < 4; ++it)
    __builtin_amdgcn_global_load_lds(
      (const __attribute__((address_space(1))) void*)(sgbase + it*16384),
      (__attribute__((address_space(3))) void*)&httile[0][w*32 + it*8][0], 16, 0, 0);
  aA0 = *(const f32x4*)(adjL);      aA1 = *(const f32x4*)(adjL + 4);
  dA0 = *(const f32x4*)(sdbL);      dA1 = *(const f32x4*)(sdbL + 4);
  aB0 = *(const f32x4*)(adjL + 64); aB1 = *(const f32x4*)(adjL + 68);
  dB0 = *(const f32x4*)(sdbL + 64); dB1 = *(const f32x4*)(sdbL + 68);

#define K3_STEP(JB, BUF, DO_STAGE, DO_REFILL, VMSTR, AV0, AV1, DV0, DV1) do{     \
    if (DO_STAGE){                                                               \
      _Pragma("unroll")                                                          \
      for (int it = 0; it < 4; ++it)                                             \
        __builtin_amdgcn_global_load_lds(                                        \
          (const __attribute__((address_space(1))) void*)(sgbase + (JB) + 64 + it*16384), \
          (__attribute__((address_space(3))) void*)&httile[(BUF)^1][w*32 + it*8][0], 16, 0, 0); \
    }                                                                            \
    {  float wv[8];                                                              \
       _Pragma("unroll")                                                         \
       for (int e = 0; e < 4; ++e){                                              \
         wv[e]   = AV0[e] + fast_exp2(lrelu(siL + DV0[e]) - Ci);                 \
         wv[4+e] = AV1[e] + fast_exp2(lrelu(siL + DV1[e]) - Ci);                 \
       }                                                                         \
       const unsigned p01 = __builtin_amdgcn_perm(__float_as_uint(wv[1]), __float_as_uint(wv[0]), 0x07060302u); \
       const unsigned p23 = __builtin_amdgcn_perm(__float_as_uint(wv[3]), __float_as_uint(wv[2]), 0x07060302u); \
       const unsigned p45 = __builtin_amdgcn_perm(__float_as_uint(wv[5]), __float_as_uint(wv[4]), 0x07060302u); \
       const unsigned p67 = __builtin_amdgcn_perm(__float_as_uint(wv[7]), __float_as_uint(wv[6]), 0x07060302u); \
       int4v ai = {(int)p01, (int)p23, (int)p45, (int)p67};                      \
       *(int4v*)&wtile[BUF][r32][wchunk*8] = ai;                                 \
    }                                                                            \
    if (DO_REFILL){                                                              \
      AV0 = *(const f32x4*)(adjL + (JB) + 128);                                  \
      AV1 = *(const f32x4*)(adjL + (JB) + 132);                                  \
      DV0 = *(const f32x4*)(sdbL + (JB) + 128);                                  \
      DV1 = *(const f32x4*)(sdbL + (JB) + 132);                                  \
    }                                                                            \
    asm volatile("s_waitcnt vmcnt(" VMSTR ") lgkmcnt(0)" ::: "memory");          \
    __builtin_amdgcn_sched_barrier(0);                                           \
    __builtin_amdgcn_s_barrier();                                                \
    __builtin_amdgcn_sched_barrier(0);                                           \
    __builtin_amdgcn_s_setprio(1);                                               \
    _Pragma("unroll")                                                            \
    for (int g = 0; g < 4; ++g){                                                 \
      const int pos = ((2*g + hl) ^ r7) * 8;                                     \
      const bf16x8 afr = *(const bf16x8*)&wtile[BUF][r32][pos];                  \
      const bf16x8 bfr = *(const bf16x8*)&httile[BUF][w*32 + r32][pos];          \
      acc = __builtin_amdgcn_mfma_f32_32x32x16_bf16(afr, bfr, acc, 0, 0, 0);     \
    }                                                                            \
    __builtin_amdgcn_s_setprio(0);                                               \
    __builtin_amdgcn_sched_barrier(0);                                           \
  }while(0)

  for (int kt = 0; kt < 30; kt += 2){
    const int jb0 = kt * 64;
    K3_STEP(jb0,      0, 1, 1, "8", aA0, aA1, dA0, dA1);
    K3_STEP(jb0 + 64, 1, 1, 1, "8", aB0, aB1, dB0, dB1);
  }
  K3_STEP(1920, 0, 1, 0, "8", aA0, aA1, dA0, dA1);  // s=30: stage tile 31
  K3_STEP(1984, 1, 0, 0, "0", aB0, aB1, dB0, dB1);  // s=31: final
#undef K3_STEP

  // ---- epilogue: direct store (full-K acc per wave) ----
#pragma unroll
  for (int rg = 0; rg < 16; ++rg){
    const int rr = (rg & 3) + 8*(rg >> 2) + 4*hl;
    out[((long)b*2048 + i0 + rr)*128 + w*32 + r32] = lrelu(acc[rg]);
  }
}

extern "C" void kernel_launch(void* const* d_in, const int* in_sizes, int n_in,
                              void* d_out, int out_size, void* d_ws, size_t ws_size,
                              hipStream_t stream){
  const float* x   = (const float*)d_in[0];
  const float* adj = (const float*)d_in[1];
  const float* W   = (const float*)d_in[2];
  const float* a   = (const float*)d_in[3];
  float* out = (float*)d_out;
  char* ws = (char*)d_ws;

  unsigned short* ht    = (unsigned short*)(ws);              // 4 MB
  float*          ssrcL = (float*)(ws + 4194304);             // 64 KB
  float*          sdstL = (float*)(ws + 4259840);             // 64 KB
  float*          carr  = (float*)(ws + 4325376);             // 64 KB
  unsigned short* Wt    = (unsigned short*)(ws + 4390912);    // 32 KB

  k0_wt   <<<1,    256, 0, stream>>>(W, Wt);
  k1_fused<<<512,  256, 0, stream>>>(x, Wt, a, ht, ssrcL, sdstL);
  k2_ml   <<<4096, 256, 0, stream>>>(ssrcL, sdstL, carr);
  k3_main <<<512,  256, 0, stream>>>(adj, ht, ssrcL, sdstL, carr, out);
}